// Round 8
// baseline (187.419 us; speedup 1.0000x reference)
//
#include <hip/hip_runtime.h>
#include <hip/hip_bf16.h>
#include <math.h>

constexpr int BB = 2;
constexpr int TT = 2048;
constexpr int EE = 1024;
constexpr int HH = 16;
constexpr int DD = 64;

typedef __bf16 v8bf __attribute__((ext_vector_type(8)));
typedef __bf16 v4bf __attribute__((ext_vector_type(4)));
typedef short  v4s  __attribute__((ext_vector_type(4)));
typedef float  v4f  __attribute__((ext_vector_type(4)));

#define MFMA16(a, b, c) __builtin_amdgcn_mfma_f32_16x16x32_bf16(a, b, c, 0, 0, 0)
#define MFMA16K16(a, b, c) __builtin_amdgcn_mfma_f32_16x16x16bf16_1k(a, b, c, 0, 0, 0)

// async global -> LDS, 16 B per lane; LDS dest = wave-uniform base + lane*16
__device__ __forceinline__ void gll16(const void* g, void* l) {
    __builtin_amdgcn_global_load_lds(
        (const __attribute__((address_space(1))) unsigned int*)g,
        (__attribute__((address_space(3))) unsigned int*)(unsigned)(uintptr_t)l,
        16, 0, 0);
}

// ---------------------------------------------------------------------------
// cast_all: x -> x_hi (bf16), wv_w -> bf16, out_w -> bf16.  8 elems/thread.
// ---------------------------------------------------------------------------
__global__ __launch_bounds__(256) void cast_all(
    const float* __restrict__ x, const float* __restrict__ wv,
    const float* __restrict__ ow,
    __bf16* __restrict__ xhi, __bf16* __restrict__ wvb, __bf16* __restrict__ owb)
{
    const int bid = blockIdx.x;
    const float* src;
    __bf16* dst;
    int base;
    if (bid < 2048)      { src = x;  dst = xhi; base = bid; }
    else if (bid < 2560) { src = wv; dst = wvb; base = bid - 2048; }
    else                 { src = ow; dst = owb; base = bid - 2560; }
    const size_t i = (size_t)base * 256 + threadIdx.x;
    float4 f0 = ((const float4*)src)[i * 2];
    float4 f1 = ((const float4*)src)[i * 2 + 1];
    float f[8] = {f0.x, f0.y, f0.z, f0.w, f1.x, f1.y, f1.z, f1.w};
    v8bf h;
    #pragma unroll
    for (int j = 0; j < 8; ++j) h[j] = (__bf16)f[j];
    *(v8bf*)(dst + i * 8) = h;
}

// ---------------------------------------------------------------------------
// bf16 MFMA GEMM: C[M,N] = A @ Bw^T + bias
// Tile 128(M) x 64(N), BK=32, 256 threads (4 waves, 2x2 grid of 64x32).
// Grid 512 blocks -> 2 blocks/CU (cross-block drain hiding).
// gll16 staging into unpadded [row][32] LDS with XOR chunk swizzle:
//   physical 16B chunk c_phys = c_log ^ ((row>>1)&3)
// Write side: the 4 lanes of a row fetch the row's same 64 B (permuted) ->
// coalescing unchanged.  Read side: 16 l15-lanes spread over all 8
// bank-quads, 2 each -> conflict-free.
// MODE 0: C fp32 row-major; MODE 1: C bf16 as vxT (B,H,D,T)
// ---------------------------------------------------------------------------
template <int MODE>
__global__ __launch_bounds__(256) void gemm_bf16(
    const __bf16* __restrict__ A, const __bf16* __restrict__ Bw,
    const float* __restrict__ bias, void* __restrict__ Cout,
    int M, int N, int K)
{
    __shared__ __bf16 Ah[2][128][32];
    __shared__ __bf16 Bh[2][64][32];

    const int tid = threadIdx.x;
    const int w = tid >> 6, lane = tid & 63, quad = lane >> 4, l15 = lane & 15;
    const int m0 = blockIdx.y * 128, n0 = blockIdx.x * 64;
    const int wm = (w >> 1) * 64, wn = (w & 1) * 32;

    v4f acc[4][2] = {};
    float bn[2];
    #pragma unroll
    for (int ns = 0; ns < 2; ++ns) bn[ns] = bias[n0 + wn + ns * 16 + l15];

    // staging rounds j=0,1: A rows 64j+16w+(lane>>2); j=2: B rows 16w+(lane>>2)
    // lane's swizzled logical chunk: (lane&3) ^ ((row>>1)&3)
    const int lrow = lane >> 2;
    int srow[3];
    const __bf16* gsrc[3];
    srow[0] = 16 * w + lrow;
    srow[1] = 64 + 16 * w + lrow;
    srow[2] = 16 * w + lrow;
    #pragma unroll
    for (int j = 0; j < 3; ++j) {
        const int clog = (lane & 3) ^ ((srow[j] >> 1) & 3);
        if (j < 2) gsrc[j] = A + (size_t)(m0 + srow[j]) * K + clog * 8;
        else       gsrc[j] = Bw + (size_t)(n0 + srow[j]) * K + clog * 8;
    }

    // prologue: tile 0 -> buf 0
    gll16(gsrc[0], &Ah[0][16 * w][0]);
    gll16(gsrc[1], &Ah[0][64 + 16 * w][0]);
    gll16(gsrc[2], &Bh[0][16 * w][0]);
    __syncthreads();

    const int NIT = K / 32;
    for (int i = 0; i < NIT; ++i) {
        const int p = i & 1;
        if (i + 1 < NIT) {
            const size_t ko = (size_t)(i + 1) * 32;
            gll16(gsrc[0] + ko, &Ah[1 - p][16 * w][0]);
            gll16(gsrc[1] + ko, &Ah[1 - p][64 + 16 * w][0]);
            gll16(gsrc[2] + ko, &Bh[1 - p][16 * w][0]);
        }
        v8bf af[4], bf2[2];
        #pragma unroll
        for (int ms = 0; ms < 4; ++ms) {
            const int r = wm + ms * 16 + l15;
            af[ms] = *(const v8bf*)&Ah[p][r][(quad ^ ((r >> 1) & 3)) * 8];
        }
        #pragma unroll
        for (int ns = 0; ns < 2; ++ns) {
            const int r = wn + ns * 16 + l15;
            bf2[ns] = *(const v8bf*)&Bh[p][r][(quad ^ ((r >> 1) & 3)) * 8];
        }
        #pragma unroll
        for (int ms = 0; ms < 4; ++ms)
            #pragma unroll
            for (int ns = 0; ns < 2; ++ns)
                acc[ms][ns] = MFMA16(af[ms], bf2[ns], acc[ms][ns]);
        __syncthreads();  // drains prefetch (vmcnt) + buffer swap
    }

    #pragma unroll
    for (int ms = 0; ms < 4; ++ms) {
        const int mbase = m0 + wm + ms * 16 + quad * 4;
        #pragma unroll
        for (int ns = 0; ns < 2; ++ns) {
            const int n = n0 + wn + ns * 16 + l15;
            if (MODE == 0) {
                float* C = (float*)Cout;
                #pragma unroll
                for (int r = 0; r < 4; ++r)
                    C[(size_t)(mbase + r) * N + n] = acc[ms][ns][r] + bn[ns];
            } else {
                const int bq = mbase >> 11, t = mbase & 2047;
                const int hh = n >> 6, dd = n & 63;
                v4bf pk;
                #pragma unroll
                for (int r = 0; r < 4; ++r) pk[r] = (__bf16)(acc[ms][ns][r] + bn[ns]);
                *(v4bf*)((__bf16*)Cout + (((size_t)bq * HH + hh) * DD + dd) * TT + t) = pk;
            }
        }
    }
}

// ---------------------------------------------------------------------------
// MFMA flash attention (round-6, unchanged): max-free softmax, P in regs via
// S^T = K·Q^T; l per-lane; LDS 36.9 KB -> 4 blocks/CU.
// ---------------------------------------------------------------------------
__global__ __launch_bounds__(256, 4) void attn_mfma(
    const float* __restrict__ x,      // (B,T,E) fp32 (phase-0 Q input)
    const __bf16* __restrict__ xh,    // (B,T,E) bf16 (K)
    const float* __restrict__ watt,   // (H,D,D) fp32
    const __bf16* __restrict__ vxT,   // (B,H,D,T) bf16
    __bf16* __restrict__ o)           // (B,T,E) bf16
{
    constexpr int LDP = 72;
    __shared__ __bf16 Khi[64][LDP];
    __shared__ __bf16 Vt[64][LDP];
    __shared__ __bf16 Pm[64][LDP];   // phase 0 only: X_hi, then Q_hi
    __shared__ __bf16 Xlo[64][LDP];  // phase 0 only: X_lo, then Q_lo

    const int tid = threadIdx.x;
    const int w = tid >> 6, lane = tid & 63, quad = lane >> 4, l15 = lane & 15;
    const int qt = blockIdx.x, h = blockIdx.y, b = blockIdx.z;
    const int t0 = qt * 64;

    // ---- phase 0: stage X q-tile (fp32 -> hi/lo) and W_h^T (scaled, hi/lo)
    {
        const int r = tid >> 2, c0 = (tid & 3) * 16;
        const float* xp = x + ((size_t)(b * TT + t0 + r)) * EE + h * DD + c0;
        #pragma unroll
        for (int c = 0; c < 2; ++c) {
            float4 f0 = ((const float4*)xp)[c * 2];
            float4 f1 = ((const float4*)xp)[c * 2 + 1];
            float f[8] = {f0.x, f0.y, f0.z, f0.w, f1.x, f1.y, f1.z, f1.w};
            v8bf hi, lo;
            #pragma unroll
            for (int j = 0; j < 8; ++j) {
                __bf16 hv = (__bf16)f[j];
                hi[j] = hv;
                lo[j] = (__bf16)(f[j] - (float)hv);
            }
            *(v8bf*)&Pm[r][c0 + c * 8] = hi;
            *(v8bf*)&Xlo[r][c0 + c * 8] = lo;
        }
        const float* wp = watt + ((size_t)h * DD + r) * DD + c0;
        #pragma unroll
        for (int i = 0; i < 16; ++i) {
            const float f = wp[i] * 0.125f;  // fold 1/sqrt(D) into W
            __bf16 hv = (__bf16)f;
            Khi[c0 + i][r] = hv;                      // Wt_hi[e_out][d]
            Vt[c0 + i][r] = (__bf16)(f - (float)hv);  // Wt_lo
        }
    }
    __syncthreads();

    // ---- Q = X_hi Wt_hi + X_hi Wt_lo + X_lo Wt_hi  (wave rows 16w..16w+16)
    v4f qacc[4] = {};
    #pragma unroll
    for (int kk = 0; kk < 2; ++kk) {
        v8bf xhf = *(const v8bf*)&Pm[w * 16 + l15][kk * 32 + quad * 8];
        v8bf xlf = *(const v8bf*)&Xlo[w * 16 + l15][kk * 32 + quad * 8];
        #pragma unroll
        for (int ns = 0; ns < 4; ++ns) {
            v8bf wh = *(const v8bf*)&Khi[ns * 16 + l15][kk * 32 + quad * 8];
            v8bf wl = *(const v8bf*)&Vt[ns * 16 + l15][kk * 32 + quad * 8];
            qacc[ns] = MFMA16(xlf, wh, qacc[ns]);
            qacc[ns] = MFMA16(xhf, wl, qacc[ns]);
            qacc[ns] = MFMA16(xhf, wh, qacc[ns]);
        }
    }
    __syncthreads();  // all waves done reading Pm/Xlo/Khi/Vt

    // write Q hi/lo (C-layout scatter, wave-local rows), reload as frags
    #pragma unroll
    for (int ns = 0; ns < 4; ++ns)
        #pragma unroll
        for (int r = 0; r < 4; ++r) {
            const float f = qacc[ns][r];
            __bf16 hv = (__bf16)f;
            Pm[w * 16 + quad * 4 + r][ns * 16 + l15] = hv;
            Xlo[w * 16 + quad * 4 + r][ns * 16 + l15] = (__bf16)(f - (float)hv);
        }
    v8bf qh[2], ql[2];
    #pragma unroll
    for (int kk = 0; kk < 2; ++kk) {
        qh[kk] = *(const v8bf*)&Pm[w * 16 + l15][kk * 32 + quad * 8];
        ql[kk] = *(const v8bf*)&Xlo[w * 16 + l15][kk * 32 + quad * 8];
    }

    v4f oacc[4] = {};
    float ll = 0.f;  // per-lane: column q = l15 partial row-sum

    const __bf16* kb = xh + (size_t)b * TT * EE + h * DD;
    const __bf16* vb = vxT + ((size_t)(b * HH + h)) * DD * TT;

    const int sr = tid >> 2, scol = (tid & 3) * 16;

    // ---- main loop over 64-row s-tiles ----
    for (int s0 = 0; s0 < TT; s0 += 64) {
        uint4 kv0 = *(const uint4*)(kb + (size_t)(s0 + sr) * EE + scol);
        uint4 kv1 = *(const uint4*)(kb + (size_t)(s0 + sr) * EE + scol + 8);
        uint4 vv0 = *(const uint4*)(vb + (size_t)sr * TT + s0 + scol);
        uint4 vv1 = *(const uint4*)(vb + (size_t)sr * TT + s0 + scol + 8);
        __syncthreads();  // prior iteration's K/V readers done
        *(uint4*)&Khi[sr][scol] = kv0;
        *(uint4*)&Khi[sr][scol + 8] = kv1;
        *(uint4*)&Vt[sr][scol] = vv0;
        *(uint4*)&Vt[sr][scol + 8] = vv1;
        __syncthreads();

        // S^T = K (Q_hi + Q_lo)^T : D[m=s][n=q], A = K rows, B = Q regs
        v4f sacc[4] = {};
        #pragma unroll
        for (int kk = 0; kk < 2; ++kk)
            #pragma unroll
            for (int ss = 0; ss < 4; ++ss) {
                v8bf kf = *(const v8bf*)&Khi[ss * 16 + l15][kk * 32 + quad * 8];
                sacc[ss] = MFMA16(kf, ql[kk], sacc[ss]);
                sacc[ss] = MFMA16(kf, qh[kk], sacc[ss]);
            }

        // exp in-place (no max subtraction); pack to bf16 A-frags; l per lane
        v4s pa[4];
        #pragma unroll
        for (int ss = 0; ss < 4; ++ss) {
            v4bf pb;
            #pragma unroll
            for (int r = 0; r < 4; ++r) {
                const float p = __expf(sacc[ss][r]);
                ll += p;
                pb[r] = (__bf16)p;
            }
            union { v4bf b; v4s s; } u;
            u.b = pb;
            pa[ss] = u.s;
        }

        // O += P V : D[m=q][n=d], A = P^T-regs (k=s), B = V^T from LDS
        #pragma unroll
        for (int ss = 0; ss < 4; ++ss)
            #pragma unroll
            for (int ds = 0; ds < 4; ++ds) {
                v4s vf = *(const v4s*)&Vt[ds * 16 + l15][ss * 16 + quad * 4];
                oacc[ds] = MFMA16K16(pa[ss], vf, oacc[ds]);
            }
    }

    // ---- epilogue: total l per q (sum quads), redistribute, store O/l ----
    ll += __shfl_xor(ll, 16);
    ll += __shfl_xor(ll, 32);  // lanes with l15=q all hold total l[q]
    float inv[4];
    #pragma unroll
    for (int r = 0; r < 4; ++r)
        inv[r] = 1.0f / __shfl(ll, quad * 4 + r);  // l[q = quad*4+r]
    #pragma unroll
    for (int ds = 0; ds < 4; ++ds)
        #pragma unroll
        for (int r = 0; r < 4; ++r) {
            const float val = oacc[ds][r] * inv[r];
            o[(size_t)(b * TT + t0 + w * 16 + quad * 4 + r) * EE +
              h * DD + ds * 16 + l15] = (__bf16)val;
        }
}

// ---------------------------------------------------------------------------
extern "C" void kernel_launch(void* const* d_in, const int* in_sizes, int n_in,
                              void* d_out, int out_size, void* d_ws, size_t ws_size,
                              hipStream_t stream)
{
    const float* x     = (const float*)d_in[0];
    const float* watt  = (const float*)d_in[1];
    const float* wv_w  = (const float*)d_in[2];
    const float* wv_b  = (const float*)d_in[3];
    const float* out_w = (const float*)d_in[4];
    const float* out_b = (const float*)d_in[5];
    float* out = (float*)d_out;

    __bf16* xhi = (__bf16*)d_ws;                         // B*T*E
    __bf16* wvb = xhi + (size_t)BB * TT * EE;            // E*E
    __bf16* owb = wvb + (size_t)EE * EE;                 // E*E
    __bf16* vxT = owb + (size_t)EE * EE;                 // B*H*D*T
    __bf16* obf = vxT + (size_t)BB * HH * DD * TT;       // B*T*E

    const int M = BB * TT;  // 4096

    cast_all<<<3072, 256, 0, stream>>>(x, wv_w, out_w, xhi, wvb, owb);

    // vx = x @ wv_w^T + wv_b, written transposed bf16 as (B,H,D,T)
    gemm_bf16<1><<<dim3(EE / 64, M / 128), 256, 0, stream>>>(
        xhi, wvb, wv_b, (void*)vxT, M, EE, EE);

    // fused bilinear attention -> obf (B,T,E) bf16
    attn_mfma<<<dim3(TT / 64, HH, BB), 256, 0, stream>>>(x, xhi, watt, vxT, obf);

    // out = o @ out_w^T + out_b (fp32 out)
    gemm_bf16<0><<<dim3(EE / 64, M / 128), 256, 0, stream>>>(
        obf, owb, out_b, (void*)out, M, EE, EE);
}

// Round 9
// 175.943 us; speedup vs baseline: 1.0652x; 1.0652x over previous
//
#include <hip/hip_runtime.h>
#include <hip/hip_bf16.h>
#include <math.h>

constexpr int BB = 2;
constexpr int TT = 2048;
constexpr int EE = 1024;
constexpr int HH = 16;
constexpr int DD = 64;

typedef __bf16 v8bf __attribute__((ext_vector_type(8)));
typedef __bf16 v4bf __attribute__((ext_vector_type(4)));
typedef short  v4s  __attribute__((ext_vector_type(4)));
typedef float  v4f  __attribute__((ext_vector_type(4)));

#define MFMA16(a, b, c) __builtin_amdgcn_mfma_f32_16x16x32_bf16(a, b, c, 0, 0, 0)
#define MFMA16K16(a, b, c) __builtin_amdgcn_mfma_f32_16x16x16bf16_1k(a, b, c, 0, 0, 0)

// async global -> LDS, 16 B per lane; LDS dest = wave-uniform base + lane*16
__device__ __forceinline__ void gll16(const void* g, void* l) {
    __builtin_amdgcn_global_load_lds(
        (const __attribute__((address_space(1))) unsigned int*)g,
        (__attribute__((address_space(3))) unsigned int*)(unsigned)(uintptr_t)l,
        16, 0, 0);
}

// ---------------------------------------------------------------------------
// cast_all: x -> x_hi (bf16), wv_w -> bf16, out_w -> bf16.  8 elems/thread.
// ---------------------------------------------------------------------------
__global__ __launch_bounds__(256) void cast_all(
    const float* __restrict__ x, const float* __restrict__ wv,
    const float* __restrict__ ow,
    __bf16* __restrict__ xhi, __bf16* __restrict__ wvb, __bf16* __restrict__ owb)
{
    const int bid = blockIdx.x;
    const float* src;
    __bf16* dst;
    int base;
    if (bid < 2048)      { src = x;  dst = xhi; base = bid; }
    else if (bid < 2560) { src = wv; dst = wvb; base = bid - 2048; }
    else                 { src = ow; dst = owb; base = bid - 2560; }
    const size_t i = (size_t)base * 256 + threadIdx.x;
    float4 f0 = ((const float4*)src)[i * 2];
    float4 f1 = ((const float4*)src)[i * 2 + 1];
    float f[8] = {f0.x, f0.y, f0.z, f0.w, f1.x, f1.y, f1.z, f1.w};
    v8bf h;
    #pragma unroll
    for (int j = 0; j < 8; ++j) h[j] = (__bf16)f[j];
    *(v8bf*)(dst + i * 8) = h;
}

// ---------------------------------------------------------------------------
// bf16 MFMA GEMM: C[M,N] = A[M,K] @ Bw[N,K]^T + bias.  M=4096, N=K=1024.
// Tile 128x128, BK=32, 512 threads (8 waves, 2x4 of 64x32).
// 1D grid 256 blocks, XCD-aware swizzle: xcd = bid&7 owns a 4(n) x 8(m)
// tile region -> per-XCD L2 working set A 2MB + B 1MB < 4MB.
// gll16 staging, XOR chunk swizzle (conflict-free frag reads), depth-1
// double buffer, one barrier per K-iter.
// MODE 0: C fp32 row-major; MODE 1: C bf16 as vxT (B,H,D,T)
// ---------------------------------------------------------------------------
template <int MODE>
__global__ __launch_bounds__(512) void gemm_bf16(
    const __bf16* __restrict__ A, const __bf16* __restrict__ Bw,
    const float* __restrict__ bias, void* __restrict__ Cout,
    int M, int N, int K)
{
    __shared__ __bf16 Ah[2][128][32];
    __shared__ __bf16 Bh[2][128][32];

    const int tid = threadIdx.x;
    const int w = tid >> 6, lane = tid & 63, quad = lane >> 4, l15 = lane & 15;
    // XCD-aware block swizzle (8 XCDs, round-robin by flat id)
    const int bid = blockIdx.x;
    const int xcd = bid & 7, slot = bid >> 3;
    const int bx = (xcd & 1) * 4 + (slot & 3);     // n-tile 0..7
    const int by = (xcd >> 1) * 8 + (slot >> 2);   // m-tile 0..31
    const int m0 = by * 128, n0 = bx * 128;
    const int wm = (w >> 2) * 64, wn = (w & 3) * 32;

    v4f acc[4][2] = {};
    float bn[2];
    #pragma unroll
    for (int ns = 0; ns < 2; ++ns) bn[ns] = bias[n0 + wn + ns * 16 + l15];

    // staging: wave w covers rows [16w,16w+16) of both 128-row tiles;
    // lane's global chunk = ((lane&3) ^ ((row>>1)&3)) * 8  (XOR swizzle)
    const int srow = 16 * w + (lane >> 2);
    const int clog = (lane & 3) ^ ((srow >> 1) & 3);
    const __bf16* ag = A + (size_t)(m0 + srow) * K + clog * 8;
    const __bf16* bg = Bw + (size_t)(n0 + srow) * K + clog * 8;

    gll16(ag, &Ah[0][16 * w][0]);
    gll16(bg, &Bh[0][16 * w][0]);
    __syncthreads();

    const int NIT = K / 32;
    for (int i = 0; i < NIT; ++i) {
        const int p = i & 1;
        if (i + 1 < NIT) {
            const size_t ko = (size_t)(i + 1) * 32;
            gll16(ag + ko, &Ah[1 - p][16 * w][0]);
            gll16(bg + ko, &Bh[1 - p][16 * w][0]);
        }
        v8bf af[4], bf2[2];
        #pragma unroll
        for (int ms = 0; ms < 4; ++ms) {
            const int r = wm + ms * 16 + l15;
            af[ms] = *(const v8bf*)&Ah[p][r][(quad ^ ((r >> 1) & 3)) * 8];
        }
        #pragma unroll
        for (int ns = 0; ns < 2; ++ns) {
            const int r = wn + ns * 16 + l15;
            bf2[ns] = *(const v8bf*)&Bh[p][r][(quad ^ ((r >> 1) & 3)) * 8];
        }
        #pragma unroll
        for (int ms = 0; ms < 4; ++ms)
            #pragma unroll
            for (int ns = 0; ns < 2; ++ns)
                acc[ms][ns] = MFMA16(af[ms], bf2[ns], acc[ms][ns]);
        __syncthreads();  // drains prefetch + buffer swap
    }

    #pragma unroll
    for (int ms = 0; ms < 4; ++ms) {
        const int mbase = m0 + wm + ms * 16 + quad * 4;
        #pragma unroll
        for (int ns = 0; ns < 2; ++ns) {
            const int n = n0 + wn + ns * 16 + l15;
            if (MODE == 0) {
                float* C = (float*)Cout;
                #pragma unroll
                for (int r = 0; r < 4; ++r)
                    C[(size_t)(mbase + r) * N + n] = acc[ms][ns][r] + bn[ns];
            } else {
                const int bq = mbase >> 11, t = mbase & 2047;
                const int hh = n >> 6, dd = n & 63;
                v4bf pk;
                #pragma unroll
                for (int r = 0; r < 4; ++r) pk[r] = (__bf16)(acc[ms][ns][r] + bn[ns]);
                *(v4bf*)((__bf16*)Cout + (((size_t)bq * HH + hh) * DD + dd) * TT + t) = pk;
            }
        }
    }
}

// ---------------------------------------------------------------------------
// MFMA flash attention: 128 q-rows/block, 4 waves (wave = 32 q-rows, 2 m-reps),
// max-free softmax, P in registers via S^T = K·Q^T.
// K-frags and V-frags read from LDS ONCE, reused for both m-reps.
// LDS 55.3 KB -> 2 blocks/CU; grid 512 = all resident.
// ---------------------------------------------------------------------------
__global__ __launch_bounds__(256, 2) void attn_mfma(
    const float* __restrict__ x,      // (B,T,E) fp32 (phase-0 Q input)
    const __bf16* __restrict__ xh,    // (B,T,E) bf16 (K)
    const float* __restrict__ watt,   // (H,D,D) fp32
    const __bf16* __restrict__ vxT,   // (B,H,D,T) bf16
    __bf16* __restrict__ o)           // (B,T,E) bf16
{
    constexpr int LDP = 72;
    __shared__ __bf16 Khi[64][LDP];
    __shared__ __bf16 Vt[64][LDP];
    __shared__ __bf16 Pm[128][LDP];   // ph0: X_hi, then Q_hi scatter
    __shared__ __bf16 Xlo[128][LDP];  // ph0: X_lo, then Q_lo scatter

    const int tid = threadIdx.x;
    const int w = tid >> 6, lane = tid & 63, quad = lane >> 4, l15 = lane & 15;
    const int qt = blockIdx.x, h = blockIdx.y, b = blockIdx.z;
    const int t0 = qt * 128;

    // ---- phase 0: stage X q-tile (fp32 -> hi/lo) and W_h^T (scaled, hi/lo)
    {
        const int row = tid >> 1, half = (tid & 1) * 32;
        const float* xp = x + ((size_t)(b * TT + t0 + row)) * EE + h * DD + half;
        #pragma unroll
        for (int c = 0; c < 4; ++c) {
            float4 f0 = ((const float4*)xp)[c * 2];
            float4 f1 = ((const float4*)xp)[c * 2 + 1];
            float f[8] = {f0.x, f0.y, f0.z, f0.w, f1.x, f1.y, f1.z, f1.w};
            v8bf hi, lo;
            #pragma unroll
            for (int j = 0; j < 8; ++j) {
                __bf16 hv = (__bf16)f[j];
                hi[j] = hv;
                lo[j] = (__bf16)(f[j] - (float)hv);
            }
            *(v8bf*)&Pm[row][half + c * 8] = hi;
            *(v8bf*)&Xlo[row][half + c * 8] = lo;
        }
        const int r = tid >> 2, c0 = (tid & 3) * 16;
        const float* wp = watt + ((size_t)h * DD + r) * DD + c0;
        #pragma unroll
        for (int i = 0; i < 16; ++i) {
            const float f = wp[i] * 0.125f;  // fold 1/sqrt(D) into W
            __bf16 hv = (__bf16)f;
            Khi[c0 + i][r] = hv;                      // Wt_hi[e_out][d]
            Vt[c0 + i][r] = (__bf16)(f - (float)hv);  // Wt_lo
        }
    }
    __syncthreads();

    // ---- Q = X_hi Wt_hi + X_hi Wt_lo + X_lo Wt_hi  (wave rows 32w..32w+32)
    v4f qacc[2][4] = {};
    #pragma unroll
    for (int kk = 0; kk < 2; ++kk) {
        v8bf xhf[2], xlf[2];
        #pragma unroll
        for (int mr = 0; mr < 2; ++mr) {
            xhf[mr] = *(const v8bf*)&Pm[w * 32 + mr * 16 + l15][kk * 32 + quad * 8];
            xlf[mr] = *(const v8bf*)&Xlo[w * 32 + mr * 16 + l15][kk * 32 + quad * 8];
        }
        #pragma unroll
        for (int ns = 0; ns < 4; ++ns) {
            v8bf wh = *(const v8bf*)&Khi[ns * 16 + l15][kk * 32 + quad * 8];
            v8bf wl = *(const v8bf*)&Vt[ns * 16 + l15][kk * 32 + quad * 8];
            #pragma unroll
            for (int mr = 0; mr < 2; ++mr) {
                qacc[mr][ns] = MFMA16(xlf[mr], wh, qacc[mr][ns]);
                qacc[mr][ns] = MFMA16(xhf[mr], wl, qacc[mr][ns]);
                qacc[mr][ns] = MFMA16(xhf[mr], wh, qacc[mr][ns]);
            }
        }
    }
    __syncthreads();  // all waves done reading Pm/Xlo/Khi/Vt

    // write Q hi/lo (C-layout scatter, wave-local rows), reload as frags
    #pragma unroll
    for (int mr = 0; mr < 2; ++mr)
        #pragma unroll
        for (int ns = 0; ns < 4; ++ns)
            #pragma unroll
            for (int r = 0; r < 4; ++r) {
                const float f = qacc[mr][ns][r];
                __bf16 hv = (__bf16)f;
                Pm[w * 32 + mr * 16 + quad * 4 + r][ns * 16 + l15] = hv;
                Xlo[w * 32 + mr * 16 + quad * 4 + r][ns * 16 + l15] = (__bf16)(f - (float)hv);
            }
    v8bf qh[2][2], ql[2][2];
    #pragma unroll
    for (int mr = 0; mr < 2; ++mr)
        #pragma unroll
        for (int kk = 0; kk < 2; ++kk) {
            qh[mr][kk] = *(const v8bf*)&Pm[w * 32 + mr * 16 + l15][kk * 32 + quad * 8];
            ql[mr][kk] = *(const v8bf*)&Xlo[w * 32 + mr * 16 + l15][kk * 32 + quad * 8];
        }

    v4f oacc[2][4] = {};
    float ll[2] = {0.f, 0.f};  // per-lane partial row-sums (q = l15)

    const __bf16* kb = xh + (size_t)b * TT * EE + h * DD;
    const __bf16* vb = vxT + ((size_t)(b * HH + h)) * DD * TT;

    const int sr = tid >> 2, scol = (tid & 3) * 16;

    // ---- main loop over 64-row s-tiles ----
    for (int s0 = 0; s0 < TT; s0 += 64) {
        uint4 kv0 = *(const uint4*)(kb + (size_t)(s0 + sr) * EE + scol);
        uint4 kv1 = *(const uint4*)(kb + (size_t)(s0 + sr) * EE + scol + 8);
        uint4 vv0 = *(const uint4*)(vb + (size_t)sr * TT + s0 + scol);
        uint4 vv1 = *(const uint4*)(vb + (size_t)sr * TT + s0 + scol + 8);
        __syncthreads();  // prior iteration's K/V readers done
        *(uint4*)&Khi[sr][scol] = kv0;
        *(uint4*)&Khi[sr][scol + 8] = kv1;
        *(uint4*)&Vt[sr][scol] = vv0;
        *(uint4*)&Vt[sr][scol + 8] = vv1;
        __syncthreads();

        // S^T = K (Q_hi + Q_lo)^T : K-frag read once, used for both m-reps
        v4f sacc[2][4] = {};
        #pragma unroll
        for (int kk = 0; kk < 2; ++kk)
            #pragma unroll
            for (int ss = 0; ss < 4; ++ss) {
                v8bf kf = *(const v8bf*)&Khi[ss * 16 + l15][kk * 32 + quad * 8];
                #pragma unroll
                for (int mr = 0; mr < 2; ++mr) {
                    sacc[mr][ss] = MFMA16(kf, ql[mr][kk], sacc[mr][ss]);
                    sacc[mr][ss] = MFMA16(kf, qh[mr][kk], sacc[mr][ss]);
                }
            }

        // exp in-place; pack to bf16 A-frags; l per lane
        v4s pa[2][4];
        #pragma unroll
        for (int mr = 0; mr < 2; ++mr)
            #pragma unroll
            for (int ss = 0; ss < 4; ++ss) {
                v4bf pb;
                #pragma unroll
                for (int r = 0; r < 4; ++r) {
                    const float p = __expf(sacc[mr][ss][r]);
                    ll[mr] += p;
                    pb[r] = (__bf16)p;
                }
                union { v4bf b; v4s s; } u;
                u.b = pb;
                pa[mr][ss] = u.s;
            }

        // O += P V : V-frag read once, used for both m-reps
        #pragma unroll
        for (int ss = 0; ss < 4; ++ss)
            #pragma unroll
            for (int ds = 0; ds < 4; ++ds) {
                v4s vf = *(const v4s*)&Vt[ds * 16 + l15][ss * 16 + quad * 4];
                #pragma unroll
                for (int mr = 0; mr < 2; ++mr)
                    oacc[mr][ds] = MFMA16K16(pa[mr][ss], vf, oacc[mr][ds]);
            }
    }

    // ---- epilogue: total l per q, redistribute, store O/l ----
    #pragma unroll
    for (int mr = 0; mr < 2; ++mr) {
        float s = ll[mr];
        s += __shfl_xor(s, 16);
        s += __shfl_xor(s, 32);  // lanes with l15=q hold total l[q]
        float inv[4];
        #pragma unroll
        for (int r = 0; r < 4; ++r)
            inv[r] = 1.0f / __shfl(s, quad * 4 + r);
        #pragma unroll
        for (int ds = 0; ds < 4; ++ds)
            #pragma unroll
            for (int r = 0; r < 4; ++r) {
                const float val = oacc[mr][ds][r] * inv[r];
                o[(size_t)(b * TT + t0 + w * 32 + mr * 16 + quad * 4 + r) * EE +
                  h * DD + ds * 16 + l15] = (__bf16)val;
            }
    }
}

// ---------------------------------------------------------------------------
extern "C" void kernel_launch(void* const* d_in, const int* in_sizes, int n_in,
                              void* d_out, int out_size, void* d_ws, size_t ws_size,
                              hipStream_t stream)
{
    const float* x     = (const float*)d_in[0];
    const float* watt  = (const float*)d_in[1];
    const float* wv_w  = (const float*)d_in[2];
    const float* wv_b  = (const float*)d_in[3];
    const float* out_w = (const float*)d_in[4];
    const float* out_b = (const float*)d_in[5];
    float* out = (float*)d_out;

    __bf16* xhi = (__bf16*)d_ws;                         // B*T*E
    __bf16* wvb = xhi + (size_t)BB * TT * EE;            // E*E
    __bf16* owb = wvb + (size_t)EE * EE;                 // E*E
    __bf16* vxT = owb + (size_t)EE * EE;                 // B*H*D*T
    __bf16* obf = vxT + (size_t)BB * HH * DD * TT;       // B*T*E

    const int M = BB * TT;  // 4096

    cast_all<<<3072, 256, 0, stream>>>(x, wv_w, out_w, xhi, wvb, owb);

    // vx = x @ wv_w^T + wv_b, written transposed bf16 as (B,H,D,T)
    gemm_bf16<1><<<(M / 128) * (EE / 128), 512, 0, stream>>>(
        xhi, wvb, wv_b, (void*)vxT, M, EE, EE);

    // fused bilinear attention -> obf (B,T,E) bf16
    attn_mfma<<<dim3(TT / 128, HH, BB), 256, 0, stream>>>(x, xhi, watt, vxT, obf);

    // out = o @ out_w^T + out_b (fp32 out)
    gemm_bf16<0><<<(M / 128) * (EE / 128), 512, 0, stream>>>(
        obf, owb, out_b, (void*)out, M, EE, EE);
}